// Round 1
// baseline (11881.138 us; speedup 1.0000x reference)
//
#include <hip/hip_runtime.h>
#include <math.h>

// Problem constants
#define BN   128      // batch
#define CIN  3
#define HCn  32       // hidden channels (ODE state)
#define HHCn 128      // inner hidden channels
#define NPX  1024     // 32*32
#define PN   4        // pieces
#define NCLS 10

__device__ __forceinline__ float softplus_f(float x) {
    return fmaxf(x, 0.f) + log1pf(expf(-fabsf(x)));
}

// ---------------- augment: z = x * aug_W^T + aug_b  (1x1 conv 3->32) ----------------
__global__ __launch_bounds__(256) void k_aug(
    const float* __restrict__ x, const float* __restrict__ aW,
    const float* __restrict__ ab, float* __restrict__ z)
{
    const int b = blockIdx.x, tid = threadIdx.x;
    const size_t xb = (size_t)b * CIN * NPX;
    const size_t zb = (size_t)b * HCn * NPX;
    float xv[CIN][4];
#pragma unroll
    for (int c = 0; c < CIN; c++)
#pragma unroll
        for (int j = 0; j < 4; j++)
            xv[c][j] = x[xb + c * NPX + tid + 256 * j];
    for (int o = 0; o < HCn; o++) {
        float w0 = aW[o * 3], w1 = aW[o * 3 + 1], w2 = aW[o * 3 + 2], bb = ab[o];
#pragma unroll
        for (int j = 0; j < 4; j++) {
            float v = fmaf(w0, xv[0][j], fmaf(w1, xv[1][j], fmaf(w2, xv[2][j], bb)));
            z[zb + (size_t)o * NPX + tid + 256 * j] = v;
        }
    }
}

// ---------------- conv1: h1 = softplus(W1 * [t ; (z + alpha*k)] + b1) ----------------
// grid (8, B), 256 thr; 16 oc x 4 px per thread
__global__ __launch_bounds__(256) void k_conv1(
    const float* __restrict__ z, const float* __restrict__ kb, float alpha,
    const float* __restrict__ W1p, const float* __restrict__ b1p, float t,
    float* __restrict__ h1)
{
    const int b = blockIdx.y, ocg = blockIdx.x, tid = threadIdx.x;
    const int oc0 = ocg * 16;
    float acc[16][4];
#pragma unroll
    for (int o = 0; o < 16; o++) {
        float eb = b1p[oc0 + o] + t * W1p[(oc0 + o) * 33];   // t-channel folded into bias
#pragma unroll
        for (int j = 0; j < 4; j++) acc[o][j] = eb;
    }
    const size_t zb = (size_t)b * HCn * NPX;
    for (int ic = 0; ic < HCn; ic++) {
        float inv[4];
#pragma unroll
        for (int j = 0; j < 4; j++) {
            size_t idx = zb + (size_t)ic * NPX + tid + 256 * j;
            float v = z[idx];
            if (alpha != 0.f) v = fmaf(alpha, kb[idx], v);
            inv[j] = v;
        }
#pragma unroll
        for (int o = 0; o < 16; o++) {
            float w = W1p[(oc0 + o) * 33 + 1 + ic];
#pragma unroll
            for (int j = 0; j < 4; j++) acc[o][j] = fmaf(w, inv[j], acc[o][j]);
        }
    }
    const size_t hb = (size_t)b * HHCn * NPX;
#pragma unroll
    for (int o = 0; o < 16; o++)
#pragma unroll
        for (int j = 0; j < 4; j++)
            h1[hb + (size_t)(oc0 + o) * NPX + tid + 256 * j] = softplus_f(acc[o][j]);
}

// ---------------- conv3x3: h2 = softplus(conv3x3(h1, W2) + b2) ----------------
// grid (8, B), 256 thr; 16 oc x 4 px per thread; 4 input planes staged in LDS
__global__ __launch_bounds__(256) void k_conv3(
    const float* __restrict__ h1, const float* __restrict__ W2p,
    const float* __restrict__ b2p, float* __restrict__ h2)
{
    const int b = blockIdx.y, ocg = blockIdx.x, tid = threadIdx.x;
    const int oc0 = ocg * 16;
    __shared__ float lds[4 * 1156];   // 4 planes of 34x34 (zero-padded)
    float acc[16][4];
#pragma unroll
    for (int o = 0; o < 16; o++) {
        float bb = b2p[oc0 + o];
#pragma unroll
        for (int j = 0; j < 4; j++) acc[o][j] = bb;
    }
    int py[4], pxx[4];
#pragma unroll
    for (int j = 0; j < 4; j++) { int p = tid + 256 * j; py[j] = p >> 5; pxx[j] = p & 31; }
    const size_t hb = (size_t)b * HHCn * NPX;

    for (int s = 0; s < 32; s++) {            // 4 input channels per stage
        __syncthreads();
#pragma unroll
        for (int ic = 0; ic < 4; ic++) {
            const float* src = h1 + hb + (size_t)(s * 4 + ic) * NPX;
            for (int i = tid; i < 1156; i += 256) {
                int yy = i / 34, xx = i - yy * 34;
                float v = 0.f;
                if (yy >= 1 && yy <= 32 && xx >= 1 && xx <= 32)
                    v = src[(yy - 1) * 32 + (xx - 1)];
                lds[ic * 1156 + i] = v;
            }
        }
        __syncthreads();
        for (int ic = 0; ic < 4; ic++) {
            const int icg = s * 4 + ic;
#pragma unroll
            for (int dy = 0; dy < 3; dy++)
#pragma unroll
            for (int dx = 0; dx < 3; dx++) {
                float inv[4];
#pragma unroll
                for (int j = 0; j < 4; j++)
                    inv[j] = lds[ic * 1156 + (py[j] + dy) * 34 + (pxx[j] + dx)];
#pragma unroll
                for (int o = 0; o < 16; o++) {
                    float w = W2p[((size_t)(oc0 + o) * HHCn + icg) * 9 + dy * 3 + dx];
#pragma unroll
                    for (int j = 0; j < 4; j++) acc[o][j] = fmaf(w, inv[j], acc[o][j]);
                }
            }
        }
    }
    const size_t ob = (size_t)b * HHCn * NPX;
#pragma unroll
    for (int o = 0; o < 16; o++)
#pragma unroll
        for (int j = 0; j < 4; j++)
            h2[ob + (size_t)(oc0 + o) * NPX + tid + 256 * j] = softplus_f(acc[o][j]);
}

// ---------------- convw3: k = tanh(W3*h2 + b3), fused RK4 accumulation ----------------
// mode 0: k=v, acc=v      (k1)
// mode 1: k=v, acc+=2v    (k2,k3)
// mode 2: z += (acc+v)/6  (k4)
// grid (2, B), 256 thr; 16 oc x 4 px per thread
__global__ __launch_bounds__(256) void k_convw3(
    const float* __restrict__ h2, const float* __restrict__ W3p,
    const float* __restrict__ b3p, float* __restrict__ kb,
    float* __restrict__ accb, float* __restrict__ zb_, int mode)
{
    const int b = blockIdx.y, ocg = blockIdx.x, tid = threadIdx.x;
    const int oc0 = ocg * 16;
    float acc[16][4];
#pragma unroll
    for (int o = 0; o < 16; o++) {
        float eb = b3p[oc0 + o];
#pragma unroll
        for (int j = 0; j < 4; j++) acc[o][j] = eb;
    }
    const size_t hb = (size_t)b * HHCn * NPX;
    for (int ic = 0; ic < HHCn; ic++) {
        float inv[4];
#pragma unroll
        for (int j = 0; j < 4; j++)
            inv[j] = h2[hb + (size_t)ic * NPX + tid + 256 * j];
#pragma unroll
        for (int o = 0; o < 16; o++) {
            float w = W3p[(oc0 + o) * HHCn + ic];
#pragma unroll
            for (int j = 0; j < 4; j++) acc[o][j] = fmaf(w, inv[j], acc[o][j]);
        }
    }
    const size_t ob = (size_t)b * HCn * NPX;
#pragma unroll
    for (int o = 0; o < 16; o++)
#pragma unroll
        for (int j = 0; j < 4; j++) {
            float v = tanhf(acc[o][j]);
            size_t i = ob + (size_t)(oc0 + o) * NPX + tid + 256 * j;
            if (mode == 0)      { kb[i] = v; accb[i] = v; }
            else if (mode == 1) { kb[i] = v; accb[i] += 2.f * v; }
            else                { zb_[i] += (accb[i] + v) * (1.f / 6.f); }
        }
}

// ---------------- readout: logits[b][c] = z_flat[b] . ro_W[c] + ro_b[c] ----------------
__global__ __launch_bounds__(256) void k_logits(
    const float* __restrict__ z, const float* __restrict__ roW,
    const float* __restrict__ rob, float* __restrict__ logits)
{
    const int b = blockIdx.x, tid = threadIdx.x;
    float p[NCLS];
#pragma unroll
    for (int c = 0; c < NCLS; c++) p[c] = 0.f;
    const float* zp = z + (size_t)b * 32768;
    for (int i = tid; i < 32768; i += 256) {
        float zv = zp[i];
#pragma unroll
        for (int c = 0; c < NCLS; c++) p[c] = fmaf(zv, roW[(size_t)c * 32768 + i], p[c]);
    }
#pragma unroll
    for (int c = 0; c < NCLS; c++)
        for (int off = 32; off > 0; off >>= 1) p[c] += __shfl_down(p[c], off, 64);
    __shared__ float red[4][NCLS];
    int wid = tid >> 6, lane = tid & 63;
    if (lane == 0)
#pragma unroll
        for (int c = 0; c < NCLS; c++) red[wid][c] = p[c];
    __syncthreads();
    if (tid < NCLS) {
        float s = red[0][tid] + red[1][tid] + red[2][tid] + red[3][tid] + rob[tid];
        logits[b * NCLS + tid] = s;
    }
}

// ---------------- loss + accuracy ----------------
__global__ __launch_bounds__(128) void k_loss(
    const float* __restrict__ logits, const int* __restrict__ y,
    float* __restrict__ out)
{
    const int b = threadIdx.x;   // 0..127
    float l[NCLS];
#pragma unroll
    for (int c = 0; c < NCLS; c++) l[c] = logits[b * NCLS + c];
    float m = l[0]; int am = 0;
#pragma unroll
    for (int c = 1; c < NCLS; c++) if (l[c] > m) { m = l[c]; am = c; }
    float s = 0.f;
#pragma unroll
    for (int c = 0; c < NCLS; c++) s += expf(l[c] - m);
    float lse = m + logf(s);
    int yy = y[b];
    float loss_b = lse - l[yy];
    float corr = (am == yy) ? 1.f : 0.f;
    for (int off = 32; off > 0; off >>= 1) {
        loss_b += __shfl_down(loss_b, off, 64);
        corr   += __shfl_down(corr,   off, 64);
    }
    __shared__ float sl[2], sc[2];
    if ((b & 63) == 0) { sl[b >> 6] = loss_b; sc[b >> 6] = corr; }
    __syncthreads();
    if (b == 0) {
        out[0] = (sl[0] + sl[1]) / (float)BN;
        out[1] = sc[0] + sc[1];
    }
}

extern "C" void kernel_launch(void* const* d_in, const int* in_sizes, int n_in,
                              void* d_out, int out_size, void* d_ws, size_t ws_size,
                              hipStream_t stream) {
    const float* x   = (const float*)d_in[0];
    const int*   y   = (const int*)  d_in[1];
    const float* aW  = (const float*)d_in[2];
    const float* ab  = (const float*)d_in[3];
    const float* W1  = (const float*)d_in[4];
    const float* b1  = (const float*)d_in[5];
    const float* W2  = (const float*)d_in[6];
    const float* b2  = (const float*)d_in[7];
    const float* W3  = (const float*)d_in[8];
    const float* b3  = (const float*)d_in[9];
    const float* roW = (const float*)d_in[10];
    const float* rob = (const float*)d_in[11];
    float* out = (float*)d_out;
    float* ws  = (float*)d_ws;

    const size_t ZSZ = (size_t)BN * HCn * NPX;    // 4.19M floats
    const size_t HSZ = (size_t)BN * HHCn * NPX;   // 16.78M floats
    float* z      = ws;
    float* kb     = z + ZSZ;
    float* accb   = kb + ZSZ;
    float* h1     = accb + ZSZ;
    float* h2     = h1 + HSZ;
    float* logits = h2 + HSZ;

    k_aug<<<BN, 256, 0, stream>>>(x, aW, ab, z);

    for (int p = 0; p < PN; p++) {
        const float t0 = (float)p;
        const float alphas[4] = {0.f, 0.5f, 0.5f, 1.0f};
        const float ts[4]     = {t0, t0 + 0.5f, t0 + 0.5f, t0 + 1.0f};
        const int   idxs[4]   = {p, p, p, (p + 1 < PN ? p + 1 : PN - 1)};
        const int   modes[4]  = {0, 1, 1, 2};
        for (int e = 0; e < 4; e++) {
            const int idx = idxs[e];
            k_conv1<<<dim3(8, BN), 256, 0, stream>>>(
                z, kb, alphas[e],
                W1 + (size_t)idx * HHCn * 33, b1 + (size_t)idx * HHCn, ts[e], h1);
            k_conv3<<<dim3(8, BN), 256, 0, stream>>>(
                h1, W2 + (size_t)idx * HHCn * HHCn * 9, b2 + (size_t)idx * HHCn, h2);
            k_convw3<<<dim3(2, BN), 256, 0, stream>>>(
                h2, W3 + (size_t)idx * HCn * HHCn, b3 + (size_t)idx * HCn,
                kb, accb, z, modes[e]);
        }
    }

    k_logits<<<BN, 256, 0, stream>>>(z, roW, rob, logits);
    k_loss<<<1, 128, 0, stream>>>(logits, y, out);
}